// Round 1
// baseline (83.992 us; speedup 1.0000x reference)
//
#include <hip/hip_runtime.h>
#include <hip/hip_bf16.h>

// KeyedSensor encrypt->decrypt roundtrip.
// Algebra: invperm[perm[i]] == i, so
//   h_rec[:, i] = h[:, i] * scale[i] / scale[i] = h[:, i]
// => output is exactly x (fp32 rounding only). Pure 201 MB d2d copy.

__global__ __launch_bounds__(256) void keyed_sensor_copy(
    const float4* __restrict__ src, float4* __restrict__ dst, long n4) {
    long i = (long)blockIdx.x * blockDim.x + threadIdx.x;
    long stride = (long)gridDim.x * blockDim.x;
    for (; i < n4; i += stride) {
        dst[i] = src[i];
    }
}

extern "C" void kernel_launch(void* const* d_in, const int* in_sizes, int n_in,
                              void* d_out, int out_size, void* d_ws, size_t ws_size,
                              hipStream_t stream) {
    const float* x = (const float*)d_in[0];
    float* out = (float*)d_out;

    // out_size = N*C*H*W = 50,331,648; divisible by 4 (H*W = 65536).
    long n4 = (long)out_size / 4;

    const int block = 256;
    long blocks_needed = (n4 + block - 1) / block;
    int grid = (int)(blocks_needed < 2048 ? blocks_needed : 2048);

    keyed_sensor_copy<<<grid, block, 0, stream>>>(
        (const float4*)x, (float4*)out, n4);
}